// Round 7
// baseline (570.200 us; speedup 1.0000x reference)
//
#include <hip/hip_runtime.h>
#include <hip/hip_bf16.h>

// ---------------- static problem config ----------------
// B=2, D=8, H=128, W=128, C=96, HEADS=3, HEAD_DIM=32
// window 2x8x8 -> N=128 tokens, NWIN=1024 windows per batch elem
// SHIFT=(1,4,4), MLP=384
typedef __bf16 bf16;
typedef bf16 bf16x8 __attribute__((ext_vector_type(8)));
typedef bf16 bf16x4 __attribute__((ext_vector_type(4)));
typedef float f32x4 __attribute__((ext_vector_type(4)));

#define MFMA16(a, b, c) __builtin_amdgcn_mfma_f32_16x16x32_bf16((a), (b), (c), 0, 0, 0)

constexpr float ATT_SCALE = 0.17677669529663687f; // 1/sqrt(32)

// ---------------- workspace layout (bytes) ----------------
// wqkvT : bf16 [288][96]   @ 0        (55296 B)
// woutT : bf16 [96][96]    @ 55296    (18432 B)
// w1T   : bf16 [384][96]   @ 73728    (73728 B)
// w2T   : bf16 [96][384]   @ 147456   (73728 B)
// biasf : f32  [3][128][128] @ 221184 (196608 B)

// =====================================================================
// Setup: transpose weights to bf16 [outcol][K], build full bias table
// =====================================================================
__global__ __launch_bounds__(256) void setup_kernel(
    const float* __restrict__ w_qkv, const float* __restrict__ w_out,
    const float* __restrict__ w1, const float* __restrict__ w2,
    const float* __restrict__ rel_bias,
    bf16* __restrict__ wqkvT, bf16* __restrict__ woutT,
    bf16* __restrict__ w1T, bf16* __restrict__ w2T,
    float* __restrict__ biasf)
{
    const int i = blockIdx.x * 256 + threadIdx.x;
    if (i < 27648) { // w_qkv [96][288] -> [288][96]
        int o = i / 96, c = i % 96;
        wqkvT[i] = (bf16)w_qkv[c * 288 + o];
    }
    if (i < 9216) {  // w_out [96][96] -> [96][96]^T
        int o = i / 96, c = i % 96;
        woutT[i] = (bf16)w_out[c * 96 + o];
    }
    if (i < 36864) { // w1 [96][384] -> [384][96]
        int o = i / 96, c = i % 96;
        w1T[i] = (bf16)w1[c * 384 + o];
    }
    if (i < 36864) { // w2 [384][96] -> [96][384]
        int o = i / 384, k = i % 384;
        w2T[i] = (bf16)w2[k * 96 + o];
    }
    if (i < 49152) { // biasf[h][i][j] = rel_bias[relidx(i,j)*3 + h]
        int h = i >> 14;
        int r = (i >> 7) & 127, cj = i & 127;
        int tdi = r >> 6, thi = (r >> 3) & 7, twi = r & 7;
        int tdj = cj >> 6, thj = (cj >> 3) & 7, twj = cj & 7;
        int relidx = (tdi - tdj + 1) * 225 + (thi - thj + 7) * 15 + (twi - twj + 7);
        biasf[i] = rel_bias[relidx * 3 + h];
    }
}

// =====================================================================
// Attention kernel: one window per block, 512 threads = 8 waves.
// Wave w owns token row-tile [16w, 16w+16).
// =====================================================================
__global__ __launch_bounds__(512) void attn_kernel(
    const float* __restrict__ x,
    const float* __restrict__ gamma1, const float* __restrict__ beta1,
    const bf16* __restrict__ wqkvT, const bf16* __restrict__ woutT,
    const float* __restrict__ b_out, const float* __restrict__ biasf,
    float* __restrict__ xres)
{
    __shared__ bf16 hw[128][104];   // LN'd window tokens (pitch 104: 16B align + conflict break)
    __shared__ bf16 qb[128][40];    // Q [token][d]
    __shared__ bf16 kb[128][40];    // K [token][d]
    __shared__ bf16 vb[32][136];    // V transposed [d][token]
    __shared__ bf16 pb[128][136];   // softmax probs [row][col]
    __shared__ bf16 ao[128][104];   // attn out (heads concat) [token][inner]
    __shared__ int region[128];
    __shared__ int srcs[128];       // token -> flat token index in x

    const int tid = threadIdx.x;
    const int lane = tid & 63;
    const int wave = tid >> 6;       // 0..7
    const int l15 = lane & 15;
    const int g = lane >> 4;         // 0..3

    const int blk = blockIdx.x;
    const int bb = blk >> 10;
    const int widx = blk & 1023;
    const int wd = widx >> 8, wh = (widx >> 4) & 15, ww = widx & 15;

    // ---- Phase 0: gather (roll + window partition) + LayerNorm1 ----
    {
        const int n = tid >> 2;      // token 0..127
        const int q4 = tid & 3;      // quarter: 24 channels each
        const int td = n >> 6, th = (n >> 3) & 7, tw = n & 7;
        const int d = wd * 2 + td, h = wh * 8 + th, w = ww * 8 + tw;
        const int d0 = (d + 1) & 7;
        const int h0 = (h + 4) & 127;
        const int w0 = (w + 4) & 127;
        const int tok = ((bb * 8 + d0) * 128 + h0) * 128 + w0;
        if (q4 == 0) {
            const int rd = d < 6 ? 0 : (d < 7 ? 1 : 2);
            const int rh = h < 120 ? 0 : (h < 124 ? 1 : 2);
            const int rw = w < 120 ? 0 : (w < 124 ? 1 : 2);
            region[n] = rd * 9 + rh * 3 + rw;
            srcs[n] = tok;
        }
        const float4* xp = reinterpret_cast<const float4*>(x + (size_t)tok * 96 + q4 * 24);
        float v[24];
        float s = 0.f, ss = 0.f;
        #pragma unroll
        for (int i = 0; i < 6; ++i) {
            float4 f = xp[i];
            v[4*i+0] = f.x; v[4*i+1] = f.y; v[4*i+2] = f.z; v[4*i+3] = f.w;
            s  += f.x + f.y + f.z + f.w;
            ss += f.x*f.x + f.y*f.y + f.z*f.z + f.w*f.w;
        }
        s  += __shfl_xor(s, 1);  ss += __shfl_xor(ss, 1);
        s  += __shfl_xor(s, 2);  ss += __shfl_xor(ss, 2);
        const float mu = s * (1.f / 96.f);
        const float rstd = rsqrtf(ss * (1.f / 96.f) - mu * mu + 1e-5f);
        #pragma unroll
        for (int i = 0; i < 24; ++i) {
            const int c = q4 * 24 + i;
            hw[n][c] = (bf16)((v[i] - mu) * rstd * gamma1[c] + beta1[c]);
        }
    }
    __syncthreads();

    const int arow = wave * 16 + l15;

    // ---- per-head attention ----
    for (int head = 0; head < 3; ++head) {
        // QKV projection for this head: out cols = {Q(32), K(32), V(32)}
        {
            bf16x8 afr[3];
            #pragma unroll
            for (int ks = 0; ks < 3; ++ks)
                afr[ks] = *reinterpret_cast<const bf16x8*>(&hw[arow][ks * 32 + g * 8]);
            #pragma unroll
            for (int ct = 0; ct < 6; ++ct) {
                const int part = ct >> 1;                // 0=Q 1=K 2=V
                const int cc = (ct & 1) * 16 + l15;      // 0..31 within head
                const int ocol = part * 96 + head * 32 + cc;
                f32x4 acc = {0.f, 0.f, 0.f, 0.f};
                #pragma unroll
                for (int ks = 0; ks < 3; ++ks) {
                    const bf16x8 bfr = *reinterpret_cast<const bf16x8*>(
                        &wqkvT[(size_t)ocol * 96 + ks * 32 + g * 8]);
                    acc = MFMA16(afr[ks], bfr, acc);
                }
                if (part == 0) {
                    #pragma unroll
                    for (int r = 0; r < 4; ++r) qb[wave * 16 + g * 4 + r][cc] = (bf16)acc[r];
                } else if (part == 1) {
                    #pragma unroll
                    for (int r = 0; r < 4; ++r) kb[wave * 16 + g * 4 + r][cc] = (bf16)acc[r];
                } else {
                    bf16x4 pk;
                    #pragma unroll
                    for (int r = 0; r < 4; ++r) pk[r] = (bf16)acc[r];
                    *reinterpret_cast<bf16x4*>(&vb[cc][wave * 16 + g * 4]) = pk;
                }
            }
        }
        __syncthreads();

        // S = Q K^T  (one K=32 MFMA step per 16x16 tile)
        f32x4 sacc[8];
        {
            const bf16x8 qf = *reinterpret_cast<const bf16x8*>(&qb[arow][g * 8]);
            #pragma unroll
            for (int ct = 0; ct < 8; ++ct) {
                const bf16x8 kf = *reinterpret_cast<const bf16x8*>(&kb[ct * 16 + l15][g * 8]);
                f32x4 z = {0.f, 0.f, 0.f, 0.f};
                sacc[ct] = MFMA16(qf, kf, z);
            }
        }
        // scale + rel-bias + region mask
        int regrow[4];
        #pragma unroll
        for (int r = 0; r < 4; ++r) regrow[r] = region[wave * 16 + g * 4 + r];
        int regcol[8];
        #pragma unroll
        for (int ct = 0; ct < 8; ++ct) regcol[ct] = region[ct * 16 + l15];
        const float* bh = biasf + head * 16384;
        #pragma unroll
        for (int ct = 0; ct < 8; ++ct) {
            const int scol = ct * 16 + l15;
            #pragma unroll
            for (int r = 0; r < 4; ++r) {
                const int srow = wave * 16 + g * 4 + r;
                float sv = sacc[ct][r] * ATT_SCALE + bh[srow * 128 + scol];
                sv += (regrow[r] == regcol[ct]) ? 0.f : -1e9f;
                sacc[ct][r] = sv;
            }
        }
        // row softmax (rows live across the 16 lanes of each l15-group)
        float mx[4], sum[4], rinv[4];
        #pragma unroll
        for (int r = 0; r < 4; ++r) {
            float m = sacc[0][r];
            #pragma unroll
            for (int ct = 1; ct < 8; ++ct) m = fmaxf(m, sacc[ct][r]);
            mx[r] = m;
        }
        #pragma unroll
        for (int w2 = 1; w2 < 16; w2 <<= 1) {
            #pragma unroll
            for (int r = 0; r < 4; ++r) mx[r] = fmaxf(mx[r], __shfl_xor(mx[r], w2));
        }
        #pragma unroll
        for (int r = 0; r < 4; ++r) sum[r] = 0.f;
        #pragma unroll
        for (int ct = 0; ct < 8; ++ct) {
            #pragma unroll
            for (int r = 0; r < 4; ++r) {
                float p = __expf(sacc[ct][r] - mx[r]);
                sacc[ct][r] = p;
                sum[r] += p;
            }
        }
        #pragma unroll
        for (int w2 = 1; w2 < 16; w2 <<= 1) {
            #pragma unroll
            for (int r = 0; r < 4; ++r) sum[r] += __shfl_xor(sum[r], w2);
        }
        #pragma unroll
        for (int r = 0; r < 4; ++r) rinv[r] = 1.f / sum[r];
        // store unnormalized P (exp <= 1, fits bf16); normalize after PV
        #pragma unroll
        for (int ct = 0; ct < 8; ++ct) {
            const int scol = ct * 16 + l15;
            #pragma unroll
            for (int r = 0; r < 4; ++r)
                pb[wave * 16 + g * 4 + r][scol] = (bf16)sacc[ct][r];
        }
        // PV: out[16 x 32] per wave (P rows are this wave's own -> no barrier needed)
        {
            bf16x8 pf[4];
            #pragma unroll
            for (int ks = 0; ks < 4; ++ks)
                pf[ks] = *reinterpret_cast<const bf16x8*>(&pb[arow][ks * 32 + g * 8]);
            #pragma unroll
            for (int ct = 0; ct < 2; ++ct) {
                f32x4 oacc = {0.f, 0.f, 0.f, 0.f};
                #pragma unroll
                for (int ks = 0; ks < 4; ++ks) {
                    const bf16x8 vf = *reinterpret_cast<const bf16x8*>(
                        &vb[ct * 16 + l15][ks * 32 + g * 8]);
                    oacc = MFMA16(pf[ks], vf, oacc);
                }
                #pragma unroll
                for (int r = 0; r < 4; ++r)
                    ao[wave * 16 + g * 4 + r][head * 32 + ct * 16 + l15] =
                        (bf16)(oacc[r] * rinv[r]);
            }
        }
        __syncthreads(); // protect q/k/v/p buffers for next head; ao complete at loop end
    }

    // ---- output projection + residual scatter ----
    {
        bf16x8 af[3];
        #pragma unroll
        for (int ks = 0; ks < 3; ++ks)
            af[ks] = *reinterpret_cast<const bf16x8*>(&ao[arow][ks * 32 + g * 8]);
        int tsrc[4];
        #pragma unroll
        for (int r = 0; r < 4; ++r) tsrc[r] = srcs[wave * 16 + g * 4 + r];
        #pragma unroll
        for (int ct = 0; ct < 6; ++ct) {
            const int col = ct * 16 + l15;
            f32x4 acc = {0.f, 0.f, 0.f, 0.f};
            #pragma unroll
            for (int ks = 0; ks < 3; ++ks) {
                const bf16x8 bfr = *reinterpret_cast<const bf16x8*>(
                    &woutT[(size_t)col * 96 + ks * 32 + g * 8]);
                acc = MFMA16(af[ks], bfr, acc);
            }
            const float bo = b_out[col];
            #pragma unroll
            for (int r = 0; r < 4; ++r) {
                const size_t a = (size_t)tsrc[r] * 96 + col;
                xres[a] = x[a] + acc[r] + bo;
            }
        }
    }
}

// =====================================================================
// MLP kernel: 64 tokens per block, 256 threads = 4 waves. In-place on xres.
// =====================================================================
__device__ __forceinline__ float gelu_tanh(float v) {
    const float a = 0.7978845608028654f * (v + 0.044715f * v * v * v);
    const float e = __expf(2.f * a);
    const float t = 1.f - 2.f / (e + 1.f);   // tanh(a), overflow-safe
    return 0.5f * v * (1.f + t);
}

__global__ __launch_bounds__(256) void mlp_kernel(
    float* __restrict__ xres,
    const float* __restrict__ gamma2, const float* __restrict__ beta2,
    const bf16* __restrict__ w1T, const float* __restrict__ b1,
    const bf16* __restrict__ w2T, const float* __restrict__ b2)
{
    __shared__ bf16 hw[64][104];
    __shared__ bf16 h1[64][392];

    const int tid = threadIdx.x;
    const int lane = tid & 63;
    const int wave = tid >> 6;
    const int l15 = lane & 15;
    const int g = lane >> 4;
    const size_t tok0 = (size_t)blockIdx.x * 64;

    // ---- LayerNorm2 ----
    {
        const int n = tid >> 2, q4 = tid & 3;
        const float4* xp = reinterpret_cast<const float4*>(xres + (tok0 + n) * 96 + q4 * 24);
        float v[24];
        float s = 0.f, ss = 0.f;
        #pragma unroll
        for (int i = 0; i < 6; ++i) {
            float4 f = xp[i];
            v[4*i+0] = f.x; v[4*i+1] = f.y; v[4*i+2] = f.z; v[4*i+3] = f.w;
            s  += f.x + f.y + f.z + f.w;
            ss += f.x*f.x + f.y*f.y + f.z*f.z + f.w*f.w;
        }
        s  += __shfl_xor(s, 1);  ss += __shfl_xor(ss, 1);
        s  += __shfl_xor(s, 2);  ss += __shfl_xor(ss, 2);
        const float mu = s * (1.f / 96.f);
        const float rstd = rsqrtf(ss * (1.f / 96.f) - mu * mu + 1e-5f);
        #pragma unroll
        for (int i = 0; i < 24; ++i) {
            const int c = q4 * 24 + i;
            hw[n][c] = (bf16)((v[i] - mu) * rstd * gamma2[c] + beta2[c]);
        }
    }
    __syncthreads();

    // ---- GEMM1 (96->384) + GELU; wave covers output cols [96w, 96w+96) ----
    {
        #pragma unroll
        for (int rt = 0; rt < 4; ++rt) {
            bf16x8 af[3];
            #pragma unroll
            for (int ks = 0; ks < 3; ++ks)
                af[ks] = *reinterpret_cast<const bf16x8*>(&hw[rt * 16 + l15][ks * 32 + g * 8]);
            #pragma unroll
            for (int ct = 0; ct < 6; ++ct) {
                const int ocol = wave * 96 + ct * 16 + l15;
                f32x4 acc = {0.f, 0.f, 0.f, 0.f};
                #pragma unroll
                for (int ks = 0; ks < 3; ++ks) {
                    const bf16x8 bfr = *reinterpret_cast<const bf16x8*>(
                        &w1T[(size_t)ocol * 96 + ks * 32 + g * 8]);
                    acc = MFMA16(af[ks], bfr, acc);
                }
                const float bb1 = b1[ocol];
                #pragma unroll
                for (int r = 0; r < 4; ++r)
                    h1[rt * 16 + g * 4 + r][ocol] = (bf16)gelu_tanh(acc[r] + bb1);
            }
        }
    }
    __syncthreads();

    // ---- GEMM2 (384->96) + residual; wave = row-tile ----
    {
        const int arow = wave * 16 + l15;
        f32x4 acc[6];
        #pragma unroll
        for (int ct = 0; ct < 6; ++ct) { f32x4 z = {0.f,0.f,0.f,0.f}; acc[ct] = z; }
        #pragma unroll
        for (int ks = 0; ks < 12; ++ks) {
            const bf16x8 af = *reinterpret_cast<const bf16x8*>(&h1[arow][ks * 32 + g * 8]);
            #pragma unroll
            for (int ct = 0; ct < 6; ++ct) {
                const bf16x8 bfr = *reinterpret_cast<const bf16x8*>(
                    &w2T[(size_t)(ct * 16 + l15) * 384 + ks * 32 + g * 8]);
                acc[ct] = MFMA16(af, bfr, acc[ct]);
            }
        }
        #pragma unroll
        for (int ct = 0; ct < 6; ++ct) {
            const int col = ct * 16 + l15;
            const float bb2 = b2[col];
            #pragma unroll
            for (int r = 0; r < 4; ++r) {
                const size_t a = (tok0 + wave * 16 + g * 4 + r) * 96 + col;
                xres[a] = xres[a] + acc[ct][r] + bb2;
            }
        }
    }
}

// =====================================================================
extern "C" void kernel_launch(void* const* d_in, const int* in_sizes, int n_in,
                              void* d_out, int out_size, void* d_ws, size_t ws_size,
                              hipStream_t stream) {
    const float* x        = (const float*)d_in[0];
    const float* gamma1   = (const float*)d_in[1];
    const float* beta1    = (const float*)d_in[2];
    const float* w_qkv    = (const float*)d_in[3];
    const float* w_out    = (const float*)d_in[4];
    const float* b_out    = (const float*)d_in[5];
    const float* rel_bias = (const float*)d_in[6];
    const float* gamma2   = (const float*)d_in[7];
    const float* beta2    = (const float*)d_in[8];
    const float* w1       = (const float*)d_in[9];
    const float* b1       = (const float*)d_in[10];
    const float* w2       = (const float*)d_in[11];
    const float* b2       = (const float*)d_in[12];
    float* out = (float*)d_out;

    char* ws = (char*)d_ws;
    bf16*  wqkvT = (bf16*)(ws + 0);
    bf16*  woutT = (bf16*)(ws + 55296);
    bf16*  w1T   = (bf16*)(ws + 73728);
    bf16*  w2T   = (bf16*)(ws + 147456);
    float* biasf = (float*)(ws + 221184);

    setup_kernel<<<192, 256, 0, stream>>>(w_qkv, w_out, w1, w2, rel_bias,
                                          wqkvT, woutT, w1T, w2T, biasf);
    attn_kernel<<<2048, 512, 0, stream>>>(x, gamma1, beta1, wqkvT, woutT,
                                          b_out, biasf, out);
    mlp_kernel<<<4096, 256, 0, stream>>>(out, gamma2, beta2, w1T, b1, w2T, b2);
}

// Round 8
// 527.919 us; speedup vs baseline: 1.0801x; 1.0801x over previous
//
#include <hip/hip_runtime.h>
#include <hip/hip_bf16.h>
#include <stdint.h>

// ---------------- static problem config ----------------
// B=2, D=8, H=128, W=128, C=96, HEADS=3, HEAD_DIM=32
// window 2x8x8 -> N=128 tokens, NWIN=1024 windows per batch elem
// SHIFT=(1,4,4), MLP=384
typedef __bf16 bf16;
typedef bf16 bf16x8 __attribute__((ext_vector_type(8)));
typedef bf16 bf16x4 __attribute__((ext_vector_type(4)));
typedef float f32x4 __attribute__((ext_vector_type(4)));
typedef uint32_t u32;

#define MFMA16(a, b, c) __builtin_amdgcn_mfma_f32_16x16x32_bf16((a), (b), (c), 0, 0, 0)

constexpr float ATT_SCALE = 0.17677669529663687f; // 1/sqrt(32)

union FragU { u32 u[4]; bf16x8 v; };

__device__ __forceinline__ u32 packbf(float lo, float hi) {
    bf16 l = (bf16)lo, h = (bf16)hi;
    unsigned short ls = __builtin_bit_cast(unsigned short, l);
    unsigned short hs = __builtin_bit_cast(unsigned short, h);
    return (u32)ls | ((u32)hs << 16);
}

// Quad-shuffle transpose: MFMA C-layout [row=g*4+r][col=l15] (two 16-row k-tiles
// "even"/"odd", packed per-lane as e01/e23 and o01/o23) -> A-frag [row=l15][k=8g+e].
// Element k=8g+e of dst (l15,g) lives at src lane (l15, g'=2(g&1)(+1)), reg r'=e&3,
// k-tile = g>>1. srcA=((lane&16)<<1)|(lane&15), srcB=srcA+16, hi=(lane&32).
__device__ __forceinline__ void quad_gather(FragU& f, u32 e01, u32 e23, u32 o01, u32 o23,
                                            int srcA, int srcB, bool hi) {
    u32 a0 = (u32)__shfl((int)e01, srcA), a1 = (u32)__shfl((int)e23, srcA);
    u32 a2 = (u32)__shfl((int)o01, srcA), a3 = (u32)__shfl((int)o23, srcA);
    u32 b0 = (u32)__shfl((int)e01, srcB), b1 = (u32)__shfl((int)e23, srcB);
    u32 b2 = (u32)__shfl((int)o01, srcB), b3 = (u32)__shfl((int)o23, srcB);
    f.u[0] = hi ? a2 : a0;
    f.u[1] = hi ? a3 : a1;
    f.u[2] = hi ? b2 : b0;
    f.u[3] = hi ? b3 : b1;
}

// ---------------- workspace layout (bytes) ----------------
// wqkvT  : bf16 [288][96]    @ 0        (55296 B)
// woutT  : bf16 [96][96]     @ 55296    (18432 B)
// w1T    : bf16 [384][96]    @ 73728    (73728 B)
// w2T    : bf16 [96][384]    @ 147456   (73728 B)
// biasfT : f32  [3][128k][128q] @ 221184 (196608 B)  (TRANSPOSED: [h][j=k][i=q])

// =====================================================================
// Setup: transpose weights to bf16 [outcol][K], build transposed bias table
// =====================================================================
__global__ __launch_bounds__(256) void setup_kernel(
    const float* __restrict__ w_qkv, const float* __restrict__ w_out,
    const float* __restrict__ w1, const float* __restrict__ w2,
    const float* __restrict__ rel_bias,
    bf16* __restrict__ wqkvT, bf16* __restrict__ woutT,
    bf16* __restrict__ w1T, bf16* __restrict__ w2T,
    float* __restrict__ biasfT)
{
    const int i = blockIdx.x * 256 + threadIdx.x;
    if (i < 27648) { // w_qkv [96][288] -> [288][96]
        int o = i / 96, c = i % 96;
        wqkvT[i] = (bf16)w_qkv[c * 288 + o];
    }
    if (i < 9216) {  // w_out [96][96] -> [96][96]^T
        int o = i / 96, c = i % 96;
        woutT[i] = (bf16)w_out[c * 96 + o];
    }
    if (i < 36864) { // w1 [96][384] -> [384][96]
        int o = i / 96, c = i % 96;
        w1T[i] = (bf16)w1[c * 384 + o];
    }
    if (i < 36864) { // w2 [384][96] -> [96][384]
        int o = i / 384, k = i % 384;
        w2T[i] = (bf16)w2[k * 96 + o];
    }
    if (i < 49152) { // biasfT[h][j=k-token][i=q-token] = bias[h][i][j]
        int h = i >> 14;
        int r = (i >> 7) & 127, cj = i & 127;   // r = i(q-row), cj = j(k-col)
        int tdi = r >> 6, thi = (r >> 3) & 7, twi = r & 7;
        int tdj = cj >> 6, thj = (cj >> 3) & 7, twj = cj & 7;
        int relidx = (tdi - tdj + 1) * 225 + (thi - thj + 7) * 15 + (twi - twj + 7);
        biasfT[h * 16384 + cj * 128 + r] = rel_bias[relidx * 3 + h];
    }
}

// =====================================================================
// Attention kernel v2: one window per block, 512 threads = 8 waves.
// Swapped QK^T (S^T in regs), in-register softmax, quad-shuffle P^T,
// swapped PV, O in regs -> no pb/ao LDS. LDS 55.5 KB -> 2 blocks/CU.
// =====================================================================
__global__ __launch_bounds__(512, 4) void attn_kernel(
    const float* __restrict__ x,
    const float* __restrict__ gamma1, const float* __restrict__ beta1,
    const bf16* __restrict__ wqkvT, const bf16* __restrict__ woutT,
    const float* __restrict__ b_out, const float* __restrict__ biasfT,
    float* __restrict__ xres)
{
    __shared__ bf16 hw[128][104];   // LN'd window tokens
    __shared__ bf16 qb[128][40];    // Q [token][d]  (wave-private rows)
    __shared__ bf16 kb[128][40];    // K [token][d]  (shared)
    __shared__ bf16 vb[32][136];    // V^T [d][token] (shared)
    __shared__ int region[128];
    __shared__ int srcs[128];

    const int tid = threadIdx.x;
    const int lane = tid & 63;
    const int wave = tid >> 6;       // 0..7
    const int l15 = lane & 15;
    const int g = lane >> 4;         // 0..3

    const int blk = blockIdx.x;
    const int bb = blk >> 10;
    const int widx = blk & 1023;
    const int wd = widx >> 8, wh = (widx >> 4) & 15, ww = widx & 15;

    // ---- Phase 0: gather (roll + window partition) + LayerNorm1 ----
    {
        const int n = tid >> 2;      // token 0..127
        const int q4 = tid & 3;      // quarter: 24 channels each
        const int td = n >> 6, th = (n >> 3) & 7, tw = n & 7;
        const int d = wd * 2 + td, h = wh * 8 + th, w = ww * 8 + tw;
        const int d0 = (d + 1) & 7;
        const int h0 = (h + 4) & 127;
        const int w0 = (w + 4) & 127;
        const int tok = ((bb * 8 + d0) * 128 + h0) * 128 + w0;
        if (q4 == 0) {
            const int rd = d < 6 ? 0 : (d < 7 ? 1 : 2);
            const int rh = h < 120 ? 0 : (h < 124 ? 1 : 2);
            const int rw = w < 120 ? 0 : (w < 124 ? 1 : 2);
            region[n] = rd * 9 + rh * 3 + rw;
            srcs[n] = tok;
        }
        const float4* xp = reinterpret_cast<const float4*>(x + (size_t)tok * 96 + q4 * 24);
        float v[24];
        float s = 0.f, ss = 0.f;
        #pragma unroll
        for (int i = 0; i < 6; ++i) {
            float4 f = xp[i];
            v[4*i+0] = f.x; v[4*i+1] = f.y; v[4*i+2] = f.z; v[4*i+3] = f.w;
            s  += f.x + f.y + f.z + f.w;
            ss += f.x*f.x + f.y*f.y + f.z*f.z + f.w*f.w;
        }
        s  += __shfl_xor(s, 1);  ss += __shfl_xor(ss, 1);
        s  += __shfl_xor(s, 2);  ss += __shfl_xor(ss, 2);
        const float mu = s * (1.f / 96.f);
        const float rstd = rsqrtf(ss * (1.f / 96.f) - mu * mu + 1e-5f);
        #pragma unroll
        for (int i = 0; i < 24; ++i) {
            const int c = q4 * 24 + i;
            hw[n][c] = (bf16)((v[i] - mu) * rstd * gamma1[c] + beta1[c]);
        }
    }
    __syncthreads();

    const int arow = wave * 16 + l15;
    const int srcA = ((lane & 16) << 1) | (lane & 15);
    const int srcB = srcA + 16;
    const bool hi = (lane & 32) != 0;
    const int qreg = region[arow];

    FragU oa[3];   // out-proj A-frags, one per head (filled as heads complete)

    // ---- per-head attention ----
    #pragma unroll
    for (int head = 0; head < 3; ++head) {
        // QKV projection for this head (unchanged from baseline)
        {
            bf16x8 afr[3];
            #pragma unroll
            for (int ks = 0; ks < 3; ++ks)
                afr[ks] = *reinterpret_cast<const bf16x8*>(&hw[arow][ks * 32 + g * 8]);
            #pragma unroll
            for (int ct = 0; ct < 6; ++ct) {
                const int part = ct >> 1;                // 0=Q 1=K 2=V
                const int cc = (ct & 1) * 16 + l15;      // 0..31 within head
                const int ocol = part * 96 + head * 32 + cc;
                f32x4 acc = {0.f, 0.f, 0.f, 0.f};
                #pragma unroll
                for (int ks = 0; ks < 3; ++ks) {
                    const bf16x8 bfr = *reinterpret_cast<const bf16x8*>(
                        &wqkvT[(size_t)ocol * 96 + ks * 32 + g * 8]);
                    acc = MFMA16(afr[ks], bfr, acc);
                }
                if (part == 0) {
                    #pragma unroll
                    for (int r = 0; r < 4; ++r) qb[wave * 16 + g * 4 + r][cc] = (bf16)acc[r];
                } else if (part == 1) {
                    #pragma unroll
                    for (int r = 0; r < 4; ++r) kb[wave * 16 + g * 4 + r][cc] = (bf16)acc[r];
                } else {
                    bf16x4 pk;
                    #pragma unroll
                    for (int r = 0; r < 4; ++r) pk[r] = (bf16)acc[r];
                    *reinterpret_cast<bf16x4*>(&vb[cc][wave * 16 + g * 4]) = pk;
                }
            }
        }
        __syncthreads();

        // S^T = K Q^T : lane (l15,g) holds S[k=ct*16+g*4+r][q=arow]
        f32x4 sacc[8];
        {
            const bf16x8 qf = *reinterpret_cast<const bf16x8*>(&qb[arow][g * 8]);
            #pragma unroll
            for (int ct = 0; ct < 8; ++ct) {
                const bf16x8 kf = *reinterpret_cast<const bf16x8*>(&kb[ct * 16 + l15][g * 8]);
                f32x4 z = {0.f, 0.f, 0.f, 0.f};
                sacc[ct] = MFMA16(kf, qf, z);
            }
        }
        // scale + rel-bias (transposed table: [h][k][q], coalesced over q=l15) + mask
        {
            const float* bh = biasfT + head * 16384;
            #pragma unroll
            for (int ct = 0; ct < 8; ++ct) {
                #pragma unroll
                for (int r = 0; r < 4; ++r) {
                    const int k = ct * 16 + g * 4 + r;
                    float sv = sacc[ct][r] * ATT_SCALE + bh[k * 128 + arow];
                    sv += (region[k] == qreg) ? 0.f : -1e9f;
                    sacc[ct][r] = sv;
                }
            }
        }
        // softmax over k: in-lane reduce over 32 regs + cross-g shfl_xor(16,32)
        float m = sacc[0][0];
        #pragma unroll
        for (int ct = 0; ct < 8; ++ct)
            #pragma unroll
            for (int r = 0; r < 4; ++r) m = fmaxf(m, sacc[ct][r]);
        m = fmaxf(m, __shfl_xor(m, 16));
        m = fmaxf(m, __shfl_xor(m, 32));
        float sum = 0.f;
        #pragma unroll
        for (int ct = 0; ct < 8; ++ct)
            #pragma unroll
            for (int r = 0; r < 4; ++r) {
                float p = __expf(sacc[ct][r] - m);
                sacc[ct][r] = p;
                sum += p;
            }
        sum += __shfl_xor(sum, 16);
        sum += __shfl_xor(sum, 32);
        const float rinv = 1.f / sum;

        // pack P (unnormalized, <=1) per k-tile: P01/P23[ct]
        u32 P01[8], P23[8];
        #pragma unroll
        for (int ct = 0; ct < 8; ++ct) {
            P01[ct] = packbf(sacc[ct][0], sacc[ct][1]);
            P23[ct] = packbf(sacc[ct][2], sacc[ct][3]);
        }
        // PV swapped: D2[d][q] = sum_k V^T[d][k] P^T[q][k]
        f32x4 acc2[2];
        {
            f32x4 z = {0.f, 0.f, 0.f, 0.f};
            acc2[0] = z; acc2[1] = z;
        }
        #pragma unroll
        for (int ks = 0; ks < 4; ++ks) {
            FragU pf;
            quad_gather(pf, P01[2*ks], P23[2*ks], P01[2*ks+1], P23[2*ks+1], srcA, srcB, hi);
            #pragma unroll
            for (int dt = 0; dt < 2; ++dt) {
                const bf16x8 vf = *reinterpret_cast<const bf16x8*>(
                    &vb[dt * 16 + l15][ks * 32 + g * 8]);
                acc2[dt] = MFMA16(vf, pf.v, acc2[dt]);
            }
        }
        // O (normalized) -> quad-shuffle into out-proj A-frag for this head
        {
            u32 E01 = packbf(acc2[0][0] * rinv, acc2[0][1] * rinv);
            u32 E23 = packbf(acc2[0][2] * rinv, acc2[0][3] * rinv);
            u32 O01 = packbf(acc2[1][0] * rinv, acc2[1][1] * rinv);
            u32 O23 = packbf(acc2[1][2] * rinv, acc2[1][3] * rinv);
            quad_gather(oa[head], E01, E23, O01, O23, srcA, srcB, hi);
        }
        __syncthreads(); // protect qb/kb/vb for next head's QKV
    }

    // ---- output projection + residual scatter (A-frags from registers) ----
    {
        int tsrc[4];
        #pragma unroll
        for (int r = 0; r < 4; ++r) tsrc[r] = srcs[wave * 16 + g * 4 + r];
        #pragma unroll
        for (int ct = 0; ct < 6; ++ct) {
            const int col = ct * 16 + l15;
            f32x4 acc = {0.f, 0.f, 0.f, 0.f};
            #pragma unroll
            for (int ks = 0; ks < 3; ++ks) {
                const bf16x8 bfr = *reinterpret_cast<const bf16x8*>(
                    &woutT[(size_t)col * 96 + ks * 32 + g * 8]);
                acc = MFMA16(oa[ks].v, bfr, acc);
            }
            const float bo = b_out[col];
            #pragma unroll
            for (int r = 0; r < 4; ++r) {
                const size_t a = (size_t)tsrc[r] * 96 + col;
                xres[a] = x[a] + acc[r] + bo;
            }
        }
    }
}

// =====================================================================
// MLP kernel v2: 64 tokens/block, 256 threads = 4 waves, each wave owns
// 16 tokens. Swapped GEMM1 (D1 col = token) -> h1 entirely in registers,
// quad-shuffled into GEMM2 A-frags. Zero barriers, LDS 13.3 KB.
// =====================================================================
__device__ __forceinline__ float gelu_tanh(float v) {
    const float a = 0.7978845608028654f * (v + 0.044715f * v * v * v);
    const float e = __expf(2.f * a);
    const float t = 1.f - 2.f / (e + 1.f);   // tanh(a), overflow-safe
    return 0.5f * v * (1.f + t);
}

__global__ __launch_bounds__(256, 4) void mlp_kernel(
    float* __restrict__ xres,
    const float* __restrict__ gamma2, const float* __restrict__ beta2,
    const bf16* __restrict__ w1T, const float* __restrict__ b1,
    const bf16* __restrict__ w2T, const float* __restrict__ b2)
{
    __shared__ bf16 hw[4][16][104];   // wave-private LN'd tokens

    const int tid = threadIdx.x;
    const int lane = tid & 63;
    const int wave = tid >> 6;
    const int l15 = lane & 15;
    const int g = lane >> 4;
    const size_t trow = (size_t)blockIdx.x * 64 + wave * 16;  // wave's first token

    // ---- LayerNorm2 (wave-private: wave LNs its own 16 rows) ----
    {
        const int n = lane >> 2, q4 = lane & 3;
        const float4* xp = reinterpret_cast<const float4*>(xres + (trow + n) * 96 + q4 * 24);
        float v[24];
        float s = 0.f, ss = 0.f;
        #pragma unroll
        for (int i = 0; i < 6; ++i) {
            float4 f = xp[i];
            v[4*i+0] = f.x; v[4*i+1] = f.y; v[4*i+2] = f.z; v[4*i+3] = f.w;
            s  += f.x + f.y + f.z + f.w;
            ss += f.x*f.x + f.y*f.y + f.z*f.z + f.w*f.w;
        }
        s  += __shfl_xor(s, 1);  ss += __shfl_xor(ss, 1);
        s  += __shfl_xor(s, 2);  ss += __shfl_xor(ss, 2);
        const float mu = s * (1.f / 96.f);
        const float rstd = rsqrtf(ss * (1.f / 96.f) - mu * mu + 1e-5f);
        #pragma unroll
        for (int i = 0; i < 24; ++i) {
            const int c = q4 * 24 + i;
            hw[wave][n][c] = (bf16)((v[i] - mu) * rstd * gamma2[c] + beta2[c]);
        }
    }
    // no barrier: hw[wave] written and read only by this wave (in-order DS)

    // ---- GEMM1 swapped: D1[o][token], h1 -> packed registers ----
    bf16x8 hfr[3];
    #pragma unroll
    for (int ks = 0; ks < 3; ++ks)
        hfr[ks] = *reinterpret_cast<const bf16x8*>(&hw[wave][l15][ks * 32 + g * 8]);

    u32 pk01[24], pk23[24];   // h1 bf16 pairs: lane (l15,g) holds o = ot*16+g*4+{r} for token l15
    #pragma unroll
    for (int ot = 0; ot < 24; ++ot) {
        const float4 b1v = *reinterpret_cast<const float4*>(b1 + ot * 16 + g * 4);
        f32x4 acc = {0.f, 0.f, 0.f, 0.f};
        #pragma unroll
        for (int ks = 0; ks < 3; ++ks) {
            const bf16x8 w1f = *reinterpret_cast<const bf16x8*>(
                &w1T[(size_t)(ot * 16 + l15) * 96 + ks * 32 + g * 8]);
            acc = MFMA16(w1f, hfr[ks], acc);
        }
        pk01[ot] = packbf(gelu_tanh(acc[0] + b1v.x), gelu_tanh(acc[1] + b1v.y));
        pk23[ot] = packbf(gelu_tanh(acc[2] + b1v.z), gelu_tanh(acc[3] + b1v.w));
    }

    // ---- GEMM2: A-frags via quad-shuffle, accumulate 96 out cols ----
    const int srcA = ((lane & 16) << 1) | (lane & 15);
    const int srcB = srcA + 16;
    const bool hi = (lane & 32) != 0;

    f32x4 acc2[6];
    #pragma unroll
    for (int ct = 0; ct < 6; ++ct) { f32x4 z = {0.f,0.f,0.f,0.f}; acc2[ct] = z; }

    #pragma unroll
    for (int ks = 0; ks < 12; ++ks) {
        FragU hf;
        quad_gather(hf, pk01[2*ks], pk23[2*ks], pk01[2*ks+1], pk23[2*ks+1], srcA, srcB, hi);
        #pragma unroll
        for (int ct = 0; ct < 6; ++ct) {
            const bf16x8 w2f = *reinterpret_cast<const bf16x8*>(
                &w2T[(size_t)(ct * 16 + l15) * 384 + ks * 32 + g * 8]);
            acc2[ct] = MFMA16(hf.v, w2f, acc2[ct]);
        }
    }

    // ---- epilogue: residual add, write ----
    #pragma unroll
    for (int ct = 0; ct < 6; ++ct) {
        const int col = ct * 16 + l15;
        const float bb2 = b2[col];
        #pragma unroll
        for (int r = 0; r < 4; ++r) {
            const size_t a = (trow + g * 4 + r) * 96 + col;
            xres[a] = xres[a] + acc2[ct][r] + bb2;
        }
    }
}

// =====================================================================
extern "C" void kernel_launch(void* const* d_in, const int* in_sizes, int n_in,
                              void* d_out, int out_size, void* d_ws, size_t ws_size,
                              hipStream_t stream) {
    const float* x        = (const float*)d_in[0];
    const float* gamma1   = (const float*)d_in[1];
    const float* beta1    = (const float*)d_in[2];
    const float* w_qkv    = (const float*)d_in[3];
    const float* w_out    = (const float*)d_in[4];
    const float* b_out    = (const float*)d_in[5];
    const float* rel_bias = (const float*)d_in[6];
    const float* gamma2   = (const float*)d_in[7];
    const float* beta2    = (const float*)d_in[8];
    const float* w1       = (const float*)d_in[9];
    const float* b1       = (const float*)d_in[10];
    const float* w2       = (const float*)d_in[11];
    const float* b2       = (const float*)d_in[12];
    float* out = (float*)d_out;

    char* ws = (char*)d_ws;
    bf16*  wqkvT  = (bf16*)(ws + 0);
    bf16*  woutT  = (bf16*)(ws + 55296);
    bf16*  w1T    = (bf16*)(ws + 73728);
    bf16*  w2T    = (bf16*)(ws + 147456);
    float* biasfT = (float*)(ws + 221184);

    setup_kernel<<<192, 256, 0, stream>>>(w_qkv, w_out, w1, w2, rel_bias,
                                          wqkvT, woutT, w1T, w2T, biasfT);
    attn_kernel<<<2048, 512, 0, stream>>>(x, gamma1, beta1, wqkvT, woutT,
                                          b_out, biasfT, out);
    mlp_kernel<<<4096, 256, 0, stream>>>(out, gamma2, beta2, w1T, b1, w2T, b2);
}